// Round 5
// baseline (418.679 us; speedup 1.0000x reference)
//
#include <hip/hip_runtime.h>

// B,T,E,H from reference setup_inputs()
#define B_ 16
#define T_ 2048
#define E_ 1024
#define H_ 128

typedef short bf16x8 __attribute__((ext_vector_type(8)));
typedef float f32x4 __attribute__((ext_vector_type(4)));
typedef unsigned short u16x4 __attribute__((ext_vector_type(4)));

static __device__ __forceinline__ unsigned short f2bf(float f) {
    unsigned int u = __float_as_uint(f);
    u += 0x7FFFu + ((u >> 16) & 1u);   // round-to-nearest-even
    return (unsigned short)(u >> 16);
}
static __device__ __forceinline__ unsigned int pk2(unsigned short a, unsigned short b) {
    return (unsigned int)a | ((unsigned int)b << 16);
}
static __device__ __forceinline__ bf16x8 frag(uint4 v) {
    return __builtin_bit_cast(bf16x8, v);
}
// async global->LDS, 16 B per lane; LDS dest = wave-uniform base + lane*16
static __device__ __forceinline__ void gl16(const unsigned short* g, unsigned short* l) {
    __builtin_amdgcn_global_load_lds(
        (const __attribute__((address_space(1))) void*)g,
        (__attribute__((address_space(3))) void*)l, 16, 0, 0);
}

// ---------------------------------------------------------------------------
// Kernel A: W fp32->bf16 transposed to wt[n][k] (n = q|k|v rows, 0..383).
// ---------------------------------------------------------------------------
__global__ __launch_bounds__(256) void cvtw_kernel(
    const float* __restrict__ w0, const float* __restrict__ w1,
    const float* __restrict__ w2, unsigned short* __restrict__ wt)
{
    int g   = blockIdx.x * 256 + threadIdx.x;   // 0..49151
    int arr = g >> 14;
    int rem = g & 16383;
    int h   = rem >> 7;
    int e0  = (rem & 127) * 8;
    const float* src = (arr == 0) ? w0 : (arr == 1) ? w1 : w2;
    unsigned short b[8];
#pragma unroll
    for (int i = 0; i < 8; i++) b[i] = f2bf(src[(size_t)(e0 + i) * H_ + h]);
    uint4 o;
    o.x = pk2(b[0], b[1]); o.y = pk2(b[2], b[3]);
    o.z = pk2(b[4], b[5]); o.w = pk2(b[6], b[7]);
    *(uint4*)&wt[(size_t)(arr * 128 + h) * E_ + e0] = o;
}

// ---------------------------------------------------------------------------
// Kernel 1: QKV projection, m97-exact geometry: grid (256,3) of 128x128
// tiles (by = q|k|v), 256 thr (4 waves, wave tile 64x64, acc[4][4] = 16
// MFMA/wave/step), BK=32, double-buffered LDS (32 KB), ONE __syncthreads
// per K-step. 768 blocks = 3 blocks/CU — the m114 overlap regime (r4
// measured 2/CU -> 13% MfmaUtil; m97 measured 3/CU -> 37%).
// B staged via gl16 (2/thread/step); A reg-staged fp32->bf16 (x read
// direct, no conversion kernel; x re-reads across by-slices are L3-hits
// per r4 FETCH evidence). __launch_bounds__(256,3) caps VGPR for 3/CU.
// ---------------------------------------------------------------------------
__global__ __launch_bounds__(256, 3) void proj_kernel(
    const float* __restrict__ x,
    const unsigned short* __restrict__ wt,
    unsigned short* __restrict__ q_ws,
    unsigned short* __restrict__ kp_ws,
    unsigned short* __restrict__ vt_ws)
{
    const int m0 = blockIdx.x * 128;
    const int by = blockIdx.y;          // 0=q, 1=k, 2=v
    __shared__ __align__(16) unsigned short As[2][128 * 32];   // 8 KB each
    __shared__ __align__(16) unsigned short Bs[2][128 * 32];   // 8 KB each

    const int tid  = threadIdx.x;
    const int lane = tid & 63;
    const int w    = tid >> 6;          // 0..3
    const int quad = lane >> 4;
    const int lm   = lane & 15;
    const int rw   = (w & 1) * 64;
    const int cw   = (w >> 1) * 64;

    // B staging (gl16): wave w covers rows w*32..w*32+31 of the 128x32 tile
    const int srow = w * 32 + (lane >> 2);
    const int sch  = (lane & 3) * 8;
    const unsigned short* gb0 = wt + (size_t)(by * 128 + srow) * E_ + sch;
    const unsigned short* gb1 = gb0 + (size_t)16 * E_;

    // A reg staging: 256 thr x 16 elems = 128x32; thread -> (row tid>>1,
    // 16-col half (tid&1)*16)
    const int arow = tid >> 1;
    const int acs  = (tid & 1) * 16;
    const float* gxa = x + (size_t)(m0 + arow) * E_ + acs;

    const f32x4 z4 = {0.f, 0.f, 0.f, 0.f};
    f32x4 acc[4][4];
#pragma unroll
    for (int i = 0; i < 4; i++)
#pragma unroll
        for (int j = 0; j < 4; j++) acc[i][j] = z4;

    auto stageB = [&](int kb, int buf) {
        gl16(gb0 + kb * 32, &Bs[buf][w * 1024]);
        gl16(gb1 + kb * 32, &Bs[buf][w * 1024 + 512]);
    };
    float4 av0, av1, av2, av3;          // A pipeline registers (16 floats)
    auto ldA = [&](int kb) {
        const float* g = gxa + kb * 32;
        av0 = *(const float4*)g;
        av1 = *(const float4*)(g + 4);
        av2 = *(const float4*)(g + 8);
        av3 = *(const float4*)(g + 12);
    };
    auto writeA = [&](int buf) {
        uint4 o0, o1;
        o0.x = pk2(f2bf(av0.x), f2bf(av0.y));
        o0.y = pk2(f2bf(av0.z), f2bf(av0.w));
        o0.z = pk2(f2bf(av1.x), f2bf(av1.y));
        o0.w = pk2(f2bf(av1.z), f2bf(av1.w));
        o1.x = pk2(f2bf(av2.x), f2bf(av2.y));
        o1.y = pk2(f2bf(av2.z), f2bf(av2.w));
        o1.z = pk2(f2bf(av3.x), f2bf(av3.y));
        o1.w = pk2(f2bf(av3.z), f2bf(av3.w));
        *(uint4*)&As[buf][arow * 32 + acs]     = o0;
        *(uint4*)&As[buf][arow * 32 + acs + 8] = o1;
    };

    // prologue: tile 0 staged; tile 1's A in registers
    ldA(0);
    stageB(0, 0);
    writeA(0);
    ldA(1);

    for (int kb = 0; kb < 32; kb++) {
        const int cb = kb & 1;
        __syncthreads();   // buf[cb] published (gl16 + ds_write drained)

        // A prefetch for kb+2 into fresh regs happens after publishing kb+1
        if (kb + 1 < 32) {
            stageB(kb + 1, cb ^ 1);   // async into other buffer
            writeA(cb ^ 1);           // regs loaded last iteration
        }
        ldA((kb + 2 < 32) ? kb + 2 : 31);   // spans the MFMA body

        bf16x8 a[4], b[4];
#pragma unroll
        for (int am = 0; am < 4; am++)
            a[am] = frag(*(const uint4*)&As[cb][(rw + am * 16 + lm) * 32 + quad * 8]);
#pragma unroll
        for (int bn = 0; bn < 4; bn++)
            b[bn] = frag(*(const uint4*)&Bs[cb][(cw + bn * 16 + lm) * 32 + quad * 8]);
#pragma unroll
        for (int am = 0; am < 4; am++)
#pragma unroll
            for (int bn = 0; bn < 4; bn++)
                acc[am][bn] = __builtin_amdgcn_mfma_f32_16x16x32_bf16(
                    a[am], b[bn], acc[am][bn], 0, 0, 0);
    }

    // epilogue (r0-verified): route by blockIdx.y to q / kp / vt
    const int bb = m0 >> 11;
    const int t0 = m0 & 2047;
#pragma unroll
    for (int am = 0; am < 4; am++)
#pragma unroll
        for (int bn = 0; bn < 4; bn++) {
            const int col = cw + bn * 16 + lm;            // 0..127
            if (by == 0) {
                const int row = m0 + rw + am * 16 + quad * 4;
#pragma unroll
                for (int r = 0; r < 4; r++)
                    q_ws[(size_t)(row + r) * H_ + col] = f2bf(acc[am][bn][r]);
            } else if (by == 1) {
                const int tl = t0 + rw + am * 16 + quad * 4;
#pragma unroll
                for (int r = 0; r < 4; r++) {
                    int t = tl + r;
                    kp_ws[(size_t)(bb * 64 + (t >> 5)) * 4096 +
                          (col >> 5) * 1024 + (t & 31) * 32 + (col & 31)] =
                        f2bf(acc[am][bn][r]);
                }
            } else {
                const int tt = t0 + rw + am * 16 + quad * 4;  // 4 consecutive kv
                u16x4 p;
#pragma unroll
                for (int r = 0; r < 4; r++) p[r] = f2bf(acc[am][bn][r]);
                *(u16x4*)&vt_ws[((size_t)(bb * 64 + (tt >> 5)) * 128 + col) * 32 + (tt & 31)] = p;
            }
        }
}

// ---------------------------------------------------------------------------
// Kernel 2: causal flash attention, grid 512 (2 blocks/CU), triple-buffered
// K/V with counted vmcnt (4 gl16/wave/segment; vmcnt(4) at iter kt leaves
// only S(kt+1) outstanding => S(kt) landed), raw s_barrier, T5 setprio.
// Unchanged from r4 (frozen this round to isolate the proj experiment).
// ---------------------------------------------------------------------------
__global__ __launch_bounds__(256, 2) void attn_kernel(
    const unsigned short* __restrict__ q_ws,
    const unsigned short* __restrict__ kp_ws,
    const unsigned short* __restrict__ vt_ws,
    float* __restrict__ out)
{
    __shared__ __align__(16) unsigned short Ks[3][4096];   // [h4][row32][32]
    __shared__ __align__(16) unsigned short Vs[3][4096];   // [col128][32]
    __shared__ __align__(16) unsigned short Ps[4][16][40];

    const int bid   = blockIdx.x;
    const int batch = bid & 15;
    const int p     = (bid >> 4) & 15;
    const int tau   = (bid >> 8) ? (31 - p) : p;
    const int nkt   = 2 * tau + 2;

    const int tid  = threadIdx.x;
    const int lane = tid & 63;
    const int ww   = tid >> 6;
    const int quad = lane >> 4;
    const int lm   = lane & 15;
    const float scale = 0.08838834764831845f;  // 1/sqrt(128)

    bf16x8 ones;
#pragma unroll
    for (int i = 0; i < 8; i++) ones[i] = (short)0x3F80;
    const f32x4 z4 = {0.f, 0.f, 0.f, 0.f};

    const size_t bq = (size_t)batch * T_ * H_;
    const int so = ww * 1024 + lane * 8;       // this wave's staging quarter
    const unsigned short* Kt = kp_ws + (size_t)(batch * 64) * 4096 + so;
    const unsigned short* Vt = vt_ws + (size_t)(batch * 64) * 4096 + so;

    auto stage = [&](int t, int b) {           // exactly 4 gl16 per wave
        const unsigned short* kg = Kt + (size_t)t * 4096;
        const unsigned short* vg = Vt + (size_t)t * 4096;
        gl16(kg,       &Ks[b][ww * 1024]);
        gl16(kg + 512, &Ks[b][ww * 1024 + 512]);
        gl16(vg,       &Vs[b][ww * 1024]);
        gl16(vg + 512, &Vs[b][ww * 1024 + 512]);
    };

    // Q B-frags for this wave's 16 q-rows
    bf16x8 qf[4];
#pragma unroll
    for (int h = 0; h < 4; h++)
        qf[h] = frag(*(const uint4*)(q_ws + bq +
                 (size_t)(tau * 64 + ww * 16 + lm) * H_ + h * 32 + quad * 8));

    f32x4 o[9];
#pragma unroll
    for (int f = 0; f < 9; f++) o[f] = z4;

    // prologue: tiles 0 and 1 in flight
    stage(0, 0);
    stage(1, 1);

    for (int kt = 0; kt < nkt; kt++) {
        const int cb = kt % 3;
        // counted wait: <=4 outstanding => S(kt) landed; then publish
        asm volatile("s_waitcnt vmcnt(4) lgkmcnt(0)" ::: "memory");
        __builtin_amdgcn_sched_barrier(0);
        __builtin_amdgcn_s_barrier();
        __builtin_amdgcn_sched_barrier(0);

        // issue tile kt+2 (clamped duplicate at tail keeps count invariant;
        // its target buffer (kt+2)%3 is never read again in that case)
        int ks = kt + 2; if (ks > nkt - 1) ks = nkt - 1;
        stage(ks, (kt + 2) % 3);

        // S^T = K.Q^T: row = quad*4+r (kv), col = lm (q)
        f32x4 st0 = z4, st1 = z4;
        __builtin_amdgcn_s_setprio(1);
#pragma unroll
        for (int h = 0; h < 4; h++) {
            bf16x8 kf0 = frag(*(const uint4*)&Ks[cb][(h * 32 + lm) * 32 + quad * 8]);
            bf16x8 kf1 = frag(*(const uint4*)&Ks[cb][(h * 32 + 16 + lm) * 32 + quad * 8]);
            st0 = __builtin_amdgcn_mfma_f32_16x16x32_bf16(kf0, qf[h], st0, 0, 0, 0);
            st1 = __builtin_amdgcn_mfma_f32_16x16x32_bf16(kf1, qf[h], st1, 0, 0, 0);
        }
        __builtin_amdgcn_s_setprio(0);

        // mask + exp -> P in wave-private LDS (A layout [q][kv])
        const int qg = tau * 64 + ww * 16 + lm;
        const int k0 = kt * 32;
        u16x4 pa, pb;
#pragma unroll
        for (int r = 0; r < 4; r++) {
            int kv0 = k0 + quad * 4 + r;
            float e0 = __expf(st0[r] * scale);
            float e1 = __expf(st1[r] * scale);
            pa[r] = (kv0      <= qg) ? f2bf(e0) : (unsigned short)0;
            pb[r] = (kv0 + 16 <= qg) ? f2bf(e1) : (unsigned short)0;
        }
        *(u16x4*)&Ps[ww][lm][quad * 4]      = pa;
        *(u16x4*)&Ps[ww][lm][16 + quad * 4] = pb;
        bf16x8 pf = frag(*(const uint4*)&Ps[ww][lm][quad * 8]);

        // O += P.V ; l via all-ones B-frag in o[8]
        __builtin_amdgcn_s_setprio(1);
#pragma unroll
        for (int f = 0; f < 8; f++) {
            bf16x8 vfr = frag(*(const uint4*)&Vs[cb][(f * 16 + lm) * 32 + quad * 8]);
            o[f] = __builtin_amdgcn_mfma_f32_16x16x32_bf16(pf, vfr, o[f], 0, 0, 0);
        }
        o[8] = __builtin_amdgcn_mfma_f32_16x16x32_bf16(pf, ones, o[8], 0, 0, 0);
        __builtin_amdgcn_s_setprio(0);
    }

    // epilogue: divide by l, store fp32
    float* op = out + bq + (size_t)(tau * 64 + ww * 16) * H_;
#pragma unroll
    for (int r = 0; r < 4; r++) {
        float inv = 1.f / o[8][r];
#pragma unroll
        for (int f = 0; f < 8; f++)
            op[(size_t)(quad * 4 + r) * H_ + f * 16 + lm] = o[f][r] * inv;
    }
}

// ---------------------------------------------------------------------------
extern "C" void kernel_launch(void* const* d_in, const int* in_sizes, int n_in,
                              void* d_out, int out_size, void* d_ws, size_t ws_size,
                              hipStream_t stream)
{
    // setup_inputs() order: x, Wk, Wq, Wv
    const float* x  = (const float*)d_in[0];
    const float* Wk = (const float*)d_in[1];
    const float* Wq = (const float*)d_in[2];
    const float* Wv = (const float*)d_in[3];
    float* out = (float*)d_out;

    const size_t MH = (size_t)B_ * T_ * H_;        // 4,194,304
    unsigned short* q_ws  = (unsigned short*)d_ws;
    unsigned short* kp_ws = q_ws + MH;             // packed [b][kt][h][row][32]
    unsigned short* vt_ws = kp_ws + MH;            // packed [b][kt][col][32]
    unsigned short* wt    = vt_ws + MH;            // [384][1024] bf16

    cvtw_kernel<<<dim3(192), dim3(256), 0, stream>>>(Wq, Wk, Wv, wt);
    proj_kernel<<<dim3(256, 3), dim3(256), 0, stream>>>(x, wt, q_ws, kp_ws, vt_ws);
    attn_kernel<<<dim3(512), dim3(256), 0, stream>>>(q_ws, kp_ws, vt_ws, out);
}

// Round 6
// 292.354 us; speedup vs baseline: 1.4321x; 1.4321x over previous
//
#include <hip/hip_runtime.h>

// B,T,E,H from reference setup_inputs()
#define B_ 16
#define T_ 2048
#define E_ 1024
#define H_ 128

typedef short bf16x8 __attribute__((ext_vector_type(8)));
typedef float f32x4 __attribute__((ext_vector_type(4)));
typedef unsigned short u16x4 __attribute__((ext_vector_type(4)));

static __device__ __forceinline__ unsigned short f2bf(float f) {
    unsigned int u = __float_as_uint(f);
    u += 0x7FFFu + ((u >> 16) & 1u);   // round-to-nearest-even
    return (unsigned short)(u >> 16);
}
static __device__ __forceinline__ unsigned int pk2(unsigned short a, unsigned short b) {
    return (unsigned int)a | ((unsigned int)b << 16);
}
static __device__ __forceinline__ bf16x8 frag(uint4 v) {
    return __builtin_bit_cast(bf16x8, v);
}
// async global->LDS, 16 B per lane; LDS dest = wave-uniform base + lane*16
static __device__ __forceinline__ void gl16(const unsigned short* g, unsigned short* l) {
    __builtin_amdgcn_global_load_lds(
        (const __attribute__((address_space(1))) void*)g,
        (__attribute__((address_space(3))) void*)l, 16, 0, 0);
}

// ---------------------------------------------------------------------------
// Kernel A: W fp32->bf16 transposed to wt[n][k] (n = q|k|v rows, 0..383).
// ---------------------------------------------------------------------------
__global__ __launch_bounds__(256) void cvtw_kernel(
    const float* __restrict__ w0, const float* __restrict__ w1,
    const float* __restrict__ w2, unsigned short* __restrict__ wt)
{
    int g   = blockIdx.x * 256 + threadIdx.x;   // 0..49151
    int arr = g >> 14;
    int rem = g & 16383;
    int h   = rem >> 7;
    int e0  = (rem & 127) * 8;
    const float* src = (arr == 0) ? w0 : (arr == 1) ? w1 : w2;
    unsigned short b[8];
#pragma unroll
    for (int i = 0; i < 8; i++) b[i] = f2bf(src[(size_t)(e0 + i) * H_ + h]);
    uint4 o;
    o.x = pk2(b[0], b[1]); o.y = pk2(b[2], b[3]);
    o.z = pk2(b[4], b[5]); o.w = pk2(b[6], b[7]);
    *(uint4*)&wt[(size_t)(arr * 128 + h) * E_ + e0] = o;
}

// ---------------------------------------------------------------------------
// Kernel 1: FUSED QKV projection, 64x192 tile, grid (512,2) -> 1024 blocks
// = 4 blocks/CU (the one change vs r4's 2/CU; measured ladder 1/CU=11%,
// 2/CU=12.7% MfmaUtil, all-pipes-idle => waves/SIMD is the limiter).
// 256 thr (4 waves, wave tile 64x48, acc[4][3]) — identical per-iter shape
// to r4: B via gl16 (3/thread/step), A reg-staged fp32->bf16 (2 float4 per
// thread, 4 lanes/row = 128 B contiguous per row), ONE __syncthreads per
// K-step. by=0 covers cols 0..191, by=1 covers 192..383 of q|k|v; x is
// read 2x but L3-resident (r4 FETCH evidence: 68 MB for 134 MB x).
// LDS 32 KB (A 2x4KB + B 2x12KB), __launch_bounds__(256,4) -> 16 waves/CU.
// ---------------------------------------------------------------------------
__global__ __launch_bounds__(256, 4) void proj_kernel(
    const float* __restrict__ x,
    const unsigned short* __restrict__ wt,
    unsigned short* __restrict__ q_ws,
    unsigned short* __restrict__ kp_ws,
    unsigned short* __restrict__ vt_ws)
{
    const int m0 = blockIdx.x * 64;
    const int c0 = blockIdx.y * 192;    // column base: 0 or 192
    __shared__ __align__(16) unsigned short As[2][64 * 32];    // 4 KB each
    __shared__ __align__(16) unsigned short Bs[2][192 * 32];   // 12 KB each

    const int tid  = threadIdx.x;
    const int lane = tid & 63;
    const int w    = tid >> 6;          // 0..3
    const int quad = lane >> 4;
    const int lm   = lane & 15;
    const int wc   = w * 48;            // wave column base within tile

    // A staging: 256 thr x 8 floats = 64x32; 4 lanes/row (32 B each)
    const int arow = tid >> 2;          // 0..63
    const int acol = (tid & 3) * 8;     // 0,8,16,24
    const float* gx = x + (size_t)(m0 + arow) * E_ + acol;

    // B staging (gl16): 3 chunks of 64 rows; thread covers (tid>>2) row,
    // (tid&3)*8 col of each chunk; LDS offset = chunk*2048 + tid*8 (linear)
    const unsigned short* gw = wt + (size_t)(c0 + (tid >> 2)) * E_ + (tid & 3) * 8;

    const f32x4 z4 = {0.f, 0.f, 0.f, 0.f};
    f32x4 acc[4][3];
#pragma unroll
    for (int i = 0; i < 4; i++)
#pragma unroll
        for (int j = 0; j < 3; j++) acc[i][j] = z4;

    auto stageB = [&](int kb, int buf) {
        const unsigned short* g = gw + kb * 32;
        unsigned short* l = &Bs[buf][tid * 8];
        gl16(g,                    l);
        gl16(g + (size_t)64  * E_, l + 2048);
        gl16(g + (size_t)128 * E_, l + 4096);
    };
    auto writeA = [&](float4 v0, float4 v1, int buf) {
        uint4 o;
        o.x = pk2(f2bf(v0.x), f2bf(v0.y));
        o.y = pk2(f2bf(v0.z), f2bf(v0.w));
        o.z = pk2(f2bf(v1.x), f2bf(v1.y));
        o.w = pk2(f2bf(v1.z), f2bf(v1.w));
        *(uint4*)&As[buf][arow * 32 + acol] = o;
    };

    // prologue: tile 0 staged; tile 1's A in registers
    float4 a0 = *(const float4*)gx;
    float4 a1 = *(const float4*)(gx + 4);
    stageB(0, 0);
    writeA(a0, a1, 0);
    a0 = *(const float4*)(gx + 32);
    a1 = *(const float4*)(gx + 36);

    for (int kb = 0; kb < 32; kb++) {
        const int cb = kb & 1;
        __syncthreads();   // buf[cb] published (gl16 + ds_write drained)

        // A register prefetch for kb+2 (spans the whole iteration)
        const int kb2 = (kb + 2 < 32) ? kb + 2 : 31;
        float4 n0 = *(const float4*)(gx + kb2 * 32);
        float4 n1 = *(const float4*)(gx + kb2 * 32 + 4);
        if (kb + 1 < 32) {
            stageB(kb + 1, cb ^ 1);        // async into other buffer
            writeA(a0, a1, cb ^ 1);        // regs loaded last iteration
        }

        bf16x8 af[4], bf[3];
#pragma unroll
        for (int am = 0; am < 4; am++)
            af[am] = frag(*(const uint4*)&As[cb][(am * 16 + lm) * 32 + quad * 8]);
#pragma unroll
        for (int bn = 0; bn < 3; bn++)
            bf[bn] = frag(*(const uint4*)&Bs[cb][(wc + bn * 16 + lm) * 32 + quad * 8]);
#pragma unroll
        for (int am = 0; am < 4; am++)
#pragma unroll
            for (int bn = 0; bn < 3; bn++)
                acc[am][bn] = __builtin_amdgcn_mfma_f32_16x16x32_bf16(
                    af[am], bf[bn], acc[am][bn], 0, 0, 0);

        a0 = n0; a1 = n1;
    }

    // epilogue: route each 16-col fragment to q / kp / vt by global column
#pragma unroll
    for (int am = 0; am < 4; am++)
#pragma unroll
        for (int bn = 0; bn < 3; bn++) {
            const int gcol  = c0 + wc + bn * 16 + lm;   // 0..383
            const int sel   = gcol >> 7;                // 0=q 1=k 2=v
            const int c     = gcol & 127;
            const int rbase = m0 + am * 16 + quad * 4;
            const int bb    = rbase >> 11;
            const int t     = rbase & 2047;
            if (sel == 0) {
#pragma unroll
                for (int r = 0; r < 4; r++)
                    q_ws[(size_t)(rbase + r) * H_ + c] = f2bf(acc[am][bn][r]);
            } else if (sel == 1) {
#pragma unroll
                for (int r = 0; r < 4; r++) {
                    int tt = t + r;
                    kp_ws[(size_t)(bb * 64 + (tt >> 5)) * 4096 +
                          (c >> 5) * 1024 + (tt & 31) * 32 + (c & 31)] =
                        f2bf(acc[am][bn][r]);
                }
            } else {
                u16x4 pv;
#pragma unroll
                for (int r = 0; r < 4; r++) pv[r] = f2bf(acc[am][bn][r]);
                *(u16x4*)&vt_ws[((size_t)(bb * 64 + (t >> 5)) * 128 + c) * 32 + (t & 31)] = pv;
            }
        }
}

// ---------------------------------------------------------------------------
// Kernel 2: causal flash attention, grid 512 (2 blocks/CU), triple-buffered
// K/V with counted vmcnt (4 gl16/wave/segment; vmcnt(4) at iter kt leaves
// only S(kt+1) outstanding => S(kt) landed), raw s_barrier, T5 setprio.
// FROZEN from r4 (passed, ~45 us).
// ---------------------------------------------------------------------------
__global__ __launch_bounds__(256, 2) void attn_kernel(
    const unsigned short* __restrict__ q_ws,
    const unsigned short* __restrict__ kp_ws,
    const unsigned short* __restrict__ vt_ws,
    float* __restrict__ out)
{
    __shared__ __align__(16) unsigned short Ks[3][4096];   // [h4][row32][32]
    __shared__ __align__(16) unsigned short Vs[3][4096];   // [col128][32]
    __shared__ __align__(16) unsigned short Ps[4][16][40];

    const int bid   = blockIdx.x;
    const int batch = bid & 15;
    const int p     = (bid >> 4) & 15;
    const int tau   = (bid >> 8) ? (31 - p) : p;
    const int nkt   = 2 * tau + 2;

    const int tid  = threadIdx.x;
    const int lane = tid & 63;
    const int ww   = tid >> 6;
    const int quad = lane >> 4;
    const int lm   = lane & 15;
    const float scale = 0.08838834764831845f;  // 1/sqrt(128)

    bf16x8 ones;
#pragma unroll
    for (int i = 0; i < 8; i++) ones[i] = (short)0x3F80;
    const f32x4 z4 = {0.f, 0.f, 0.f, 0.f};

    const size_t bq = (size_t)batch * T_ * H_;
    const int so = ww * 1024 + lane * 8;       // this wave's staging quarter
    const unsigned short* Kt = kp_ws + (size_t)(batch * 64) * 4096 + so;
    const unsigned short* Vt = vt_ws + (size_t)(batch * 64) * 4096 + so;

    auto stage = [&](int t, int b) {           // exactly 4 gl16 per wave
        const unsigned short* kg = Kt + (size_t)t * 4096;
        const unsigned short* vg = Vt + (size_t)t * 4096;
        gl16(kg,       &Ks[b][ww * 1024]);
        gl16(kg + 512, &Ks[b][ww * 1024 + 512]);
        gl16(vg,       &Vs[b][ww * 1024]);
        gl16(vg + 512, &Vs[b][ww * 1024 + 512]);
    };

    // Q B-frags for this wave's 16 q-rows
    bf16x8 qf[4];
#pragma unroll
    for (int h = 0; h < 4; h++)
        qf[h] = frag(*(const uint4*)(q_ws + bq +
                 (size_t)(tau * 64 + ww * 16 + lm) * H_ + h * 32 + quad * 8));

    f32x4 o[9];
#pragma unroll
    for (int f = 0; f < 9; f++) o[f] = z4;

    // prologue: tiles 0 and 1 in flight
    stage(0, 0);
    stage(1, 1);

    for (int kt = 0; kt < nkt; kt++) {
        const int cb = kt % 3;
        // counted wait: <=4 outstanding => S(kt) landed; then publish
        asm volatile("s_waitcnt vmcnt(4) lgkmcnt(0)" ::: "memory");
        __builtin_amdgcn_sched_barrier(0);
        __builtin_amdgcn_s_barrier();
        __builtin_amdgcn_sched_barrier(0);

        // issue tile kt+2 (clamped duplicate at tail keeps count invariant;
        // its target buffer (kt+2)%3 is never read again in that case)
        int ks = kt + 2; if (ks > nkt - 1) ks = nkt - 1;
        stage(ks, (kt + 2) % 3);

        // S^T = K.Q^T: row = quad*4+r (kv), col = lm (q)
        f32x4 st0 = z4, st1 = z4;
        __builtin_amdgcn_s_setprio(1);
#pragma unroll
        for (int h = 0; h < 4; h++) {
            bf16x8 kf0 = frag(*(const uint4*)&Ks[cb][(h * 32 + lm) * 32 + quad * 8]);
            bf16x8 kf1 = frag(*(const uint4*)&Ks[cb][(h * 32 + 16 + lm) * 32 + quad * 8]);
            st0 = __builtin_amdgcn_mfma_f32_16x16x32_bf16(kf0, qf[h], st0, 0, 0, 0);
            st1 = __builtin_amdgcn_mfma_f32_16x16x32_bf16(kf1, qf[h], st1, 0, 0, 0);
        }
        __builtin_amdgcn_s_setprio(0);

        // mask + exp -> P in wave-private LDS (A layout [q][kv])
        const int qg = tau * 64 + ww * 16 + lm;
        const int k0 = kt * 32;
        u16x4 pa, pb;
#pragma unroll
        for (int r = 0; r < 4; r++) {
            int kv0 = k0 + quad * 4 + r;
            float e0 = __expf(st0[r] * scale);
            float e1 = __expf(st1[r] * scale);
            pa[r] = (kv0      <= qg) ? f2bf(e0) : (unsigned short)0;
            pb[r] = (kv0 + 16 <= qg) ? f2bf(e1) : (unsigned short)0;
        }
        *(u16x4*)&Ps[ww][lm][quad * 4]      = pa;
        *(u16x4*)&Ps[ww][lm][16 + quad * 4] = pb;
        bf16x8 pf = frag(*(const uint4*)&Ps[ww][lm][quad * 8]);

        // O += P.V ; l via all-ones B-frag in o[8]
        __builtin_amdgcn_s_setprio(1);
#pragma unroll
        for (int f = 0; f < 8; f++) {
            bf16x8 vfr = frag(*(const uint4*)&Vs[cb][(f * 16 + lm) * 32 + quad * 8]);
            o[f] = __builtin_amdgcn_mfma_f32_16x16x32_bf16(pf, vfr, o[f], 0, 0, 0);
        }
        o[8] = __builtin_amdgcn_mfma_f32_16x16x32_bf16(pf, ones, o[8], 0, 0, 0);
        __builtin_amdgcn_s_setprio(0);
    }

    // epilogue: divide by l, store fp32
    float* op = out + bq + (size_t)(tau * 64 + ww * 16) * H_;
#pragma unroll
    for (int r = 0; r < 4; r++) {
        float inv = 1.f / o[8][r];
#pragma unroll
        for (int f = 0; f < 8; f++)
            op[(size_t)(quad * 4 + r) * H_ + f * 16 + lm] = o[f][r] * inv;
    }
}

// ---------------------------------------------------------------------------
extern "C" void kernel_launch(void* const* d_in, const int* in_sizes, int n_in,
                              void* d_out, int out_size, void* d_ws, size_t ws_size,
                              hipStream_t stream)
{
    // setup_inputs() order: x, Wk, Wq, Wv
    const float* x  = (const float*)d_in[0];
    const float* Wk = (const float*)d_in[1];
    const float* Wq = (const float*)d_in[2];
    const float* Wv = (const float*)d_in[3];
    float* out = (float*)d_out;

    const size_t MH = (size_t)B_ * T_ * H_;        // 4,194,304
    unsigned short* q_ws  = (unsigned short*)d_ws;
    unsigned short* kp_ws = q_ws + MH;             // packed [b][kt][h][row][32]
    unsigned short* vt_ws = kp_ws + MH;            // packed [b][kt][col][32]
    unsigned short* wt    = vt_ws + MH;            // [384][1024] bf16

    cvtw_kernel<<<dim3(192), dim3(256), 0, stream>>>(Wq, Wk, Wv, wt);
    proj_kernel<<<dim3(512, 2), dim3(256), 0, stream>>>(x, wt, q_ws, kp_ws, vt_ws);
    attn_kernel<<<dim3(512), dim3(256), 0, stream>>>(q_ws, kp_ws, vt_ws, out);
}